// Round 1
// baseline (307.939 us; speedup 1.0000x reference)
//
#include <hip/hip_runtime.h>

#define DIM 256
#define NC 16
#define NG 1000

// ---------------------------------------------------------------------------
// Phase 1: hidden[n][c] = dot(x[n], W[:,c]) + b[c]
// Thread layout: gid -> (node = gid>>1, half = gid&1) ; each thread computes
// 8 of the 16 classes for one node. W staged in LDS (broadcast reads).
// ---------------------------------------------------------------------------
__global__ void hidden_kernel(const float* __restrict__ x,
                              const float* __restrict__ W,
                              const float* __restrict__ b,
                              float* __restrict__ hidden, int N) {
    __shared__ float Ws[DIM * NC];
    for (int i = threadIdx.x; i < DIM * NC; i += blockDim.x) Ws[i] = W[i];
    __syncthreads();

    int gid = blockIdx.x * blockDim.x + threadIdx.x;
    int n = gid >> 1;
    if (n >= N) return;
    int c0 = (gid & 1) * 8;

    float acc[8];
#pragma unroll
    for (int j = 0; j < 8; ++j) acc[j] = b[c0 + j];

    const float4* x4 = (const float4*)(x + (size_t)n * DIM);
#pragma unroll 4
    for (int d4 = 0; d4 < DIM / 4; ++d4) {
        float4 xv = x4[d4];
        const float xs[4] = {xv.x, xv.y, xv.z, xv.w};
#pragma unroll
        for (int jj = 0; jj < 4; ++jj) {
            int d = d4 * 4 + jj;
#pragma unroll
            for (int c = 0; c < 8; ++c)
                acc[c] = fmaf(xs[jj], Ws[d * NC + c0 + c], acc[c]);
        }
    }

    float4* out4 = (float4*)(hidden + (size_t)n * NC + c0);
    out4[0] = make_float4(acc[0], acc[1], acc[2], acc[3]);
    out4[1] = make_float4(acc[4], acc[5], acc[6], acc[7]);
}

// ---------------------------------------------------------------------------
// Phase 2a: node -> graph id via binary search over sorted ed_idx
// seg = #\{i : ed_idx[i] <= n\}  (searchsorted 'right'); == G for dropped nodes
// ---------------------------------------------------------------------------
__global__ void seg_kernel(const int* __restrict__ ed_idx,
                           int* __restrict__ node_seg, int N, int G) {
    int n = blockIdx.x * blockDim.x + threadIdx.x;
    if (n >= N) return;
    int lo = 0, hi = G;
    while (lo < hi) {
        int mid = (lo + hi) >> 1;
        if (ed_idx[mid] <= n) lo = mid + 1; else hi = mid;
    }
    node_seg[n] = lo;
}

// ---------------------------------------------------------------------------
// Phase 2b: fused SpMM + ragged pooling.
// pooled[g][c] += vals[e] * hidden[cols[e]][c]   where g = seg(rows[e])
// Per-block LDS accumulator of the full [NG][NC] output, merged via global
// atomics at the end.
// ---------------------------------------------------------------------------
__global__ void __launch_bounds__(512) edge_kernel(
    const int* __restrict__ rows, const int* __restrict__ cols,
    const float* __restrict__ vals, const float* __restrict__ hidden,
    const int* __restrict__ node_seg, float* __restrict__ out, int nE) {
    __shared__ float acc[NG * NC];  // 64000 B
    for (int i = threadIdx.x; i < NG * NC; i += blockDim.x) acc[i] = 0.f;
    __syncthreads();

    int stride = gridDim.x * blockDim.x;
    for (int e = blockIdx.x * blockDim.x + threadIdx.x; e < nE; e += stride) {
        int g = node_seg[rows[e]];
        if (g >= NG) continue;
        float v = vals[e];
        const float4* h4 = (const float4*)(hidden + (size_t)cols[e] * NC);
        float4 a0 = h4[0], a1 = h4[1], a2 = h4[2], a3 = h4[3];
        float* p = acc + g * NC;
        atomicAdd(p + 0,  v * a0.x);
        atomicAdd(p + 1,  v * a0.y);
        atomicAdd(p + 2,  v * a0.z);
        atomicAdd(p + 3,  v * a0.w);
        atomicAdd(p + 4,  v * a1.x);
        atomicAdd(p + 5,  v * a1.y);
        atomicAdd(p + 6,  v * a1.z);
        atomicAdd(p + 7,  v * a1.w);
        atomicAdd(p + 8,  v * a2.x);
        atomicAdd(p + 9,  v * a2.y);
        atomicAdd(p + 10, v * a2.z);
        atomicAdd(p + 11, v * a2.w);
        atomicAdd(p + 12, v * a3.x);
        atomicAdd(p + 13, v * a3.y);
        atomicAdd(p + 14, v * a3.z);
        atomicAdd(p + 15, v * a3.w);
    }
    __syncthreads();

    for (int i = threadIdx.x; i < NG * NC; i += blockDim.x)
        atomicAdd(&out[i], acc[i]);
}

extern "C" void kernel_launch(void* const* d_in, const int* in_sizes, int n_in,
                              void* d_out, int out_size, void* d_ws, size_t ws_size,
                              hipStream_t stream) {
    const float* x      = (const float*)d_in[0];
    const int*   ed_idx = (const int*)  d_in[1];
    const int*   rows   = (const int*)  d_in[2];
    const int*   cols   = (const int*)  d_in[3];
    const float* vals   = (const float*)d_in[4];
    const float* W      = (const float*)d_in[5];
    const float* b      = (const float*)d_in[6];
    float* out = (float*)d_out;

    int N  = in_sizes[0] / DIM;   // 100000
    int G  = in_sizes[1];         // 1000
    int nE = in_sizes[2];         // 3200000

    float* hidden  = (float*)d_ws;                                   // N*16 f32 = 6.4 MB
    int*   node_seg = (int*)((char*)d_ws + (size_t)N * NC * sizeof(float));  // N i32

    // Output is accumulated with atomics -> must be zeroed every call.
    hipMemsetAsync(d_out, 0, (size_t)out_size * sizeof(float), stream);

    hidden_kernel<<<(2 * N + 255) / 256, 256, 0, stream>>>(x, W, b, hidden, N);
    seg_kernel<<<(N + 255) / 256, 256, 0, stream>>>(ed_idx, node_seg, N, G);
    edge_kernel<<<512, 512, 0, stream>>>(rows, cols, vals, hidden, node_seg, out, nE);
}